// Round 3
// baseline (2113.038 us; speedup 1.0000x reference)
//
#include <hip/hip_runtime.h>
#include <hip/hip_bf16.h>
#include <math.h>

#define D_MODELc 1024
#define N_HEADSc 16
#define D_HEADc  64
#define B_SZc    4
#define L_SEQc   4096
#define EPSc     1e-6f
#define CHUNKc   128
#define NCHUNKc  (L_SEQc / CHUNKc)   // 32

// per-batch workspace element counts
#define QKV_PER_B  4194304ull        // 16*4096*64
#define ATT_PER_B  4194304ull        // 4096*1024
#define S_PER_B    2097152ull        // 16*32*64*64
#define Z_PER_B    32768ull          // 16*32*64
#define WS_PER_B   (3ull*QKV_PER_B + ATT_PER_B + S_PER_B + Z_PER_B)  // 18,907,136 floats

__device__ __forceinline__ float phi_f(float x) {
    // elu(x)+1 : x>0 ? x+1 : exp(x)
    return x > 0.0f ? x + 1.0f : expf(x);
}

// ---------------------------------------------------------------------------
// C[m][n] = sum_k A[m][k] * B[n][k]   (both row-major, K contiguous)
// MODE 0: plain store to C (row-major M x N)
// MODE 1: qkv scatter with phi on q,k  (N == 3072); b-local = m>>12
// Tile 64x64, BK=16, 256 threads, 4x4 per-thread register tile.
// ---------------------------------------------------------------------------
template<int MODE>
__global__ __launch_bounds__(256)
void gemm_nt(const float* __restrict__ A, const float* __restrict__ Bm,
             float* __restrict__ C, int M, int N, int K,
             float* __restrict__ qb, float* __restrict__ kb, float* __restrict__ vb)
{
    __shared__ float As[16][68];   // [k][m], stride 68: float4-aligned, low-conflict
    __shared__ float Bs[16][68];   // [k][n]
    const int tid = threadIdx.x;
    const int bm = blockIdx.y, bn = blockIdx.x;
    const int lr = tid >> 2;            // 0..63 row within tile
    const int lc = (tid & 3) << 2;      // k offset 0,4,8,12
    const float* Ap = A + (size_t)(bm * 64 + lr) * K + lc;
    const float* Bp = Bm + (size_t)(bn * 64 + lr) * K + lc;
    const int tx = tid & 15, ty = tid >> 4;

    float acc[4][4];
#pragma unroll
    for (int i = 0; i < 4; ++i)
#pragma unroll
        for (int j = 0; j < 4; ++j) acc[i][j] = 0.0f;

    for (int k0 = 0; k0 < K; k0 += 16) {
        float4 av = *(const float4*)(Ap + k0);
        float4 bv = *(const float4*)(Bp + k0);
        __syncthreads();
        As[lc + 0][lr] = av.x; As[lc + 1][lr] = av.y;
        As[lc + 2][lr] = av.z; As[lc + 3][lr] = av.w;
        Bs[lc + 0][lr] = bv.x; Bs[lc + 1][lr] = bv.y;
        Bs[lc + 2][lr] = bv.z; Bs[lc + 3][lr] = bv.w;
        __syncthreads();
#pragma unroll
        for (int kk = 0; kk < 16; ++kk) {
            float4 a = *(const float4*)&As[kk][ty * 4];
            float4 b = *(const float4*)&Bs[kk][tx * 4];
            float aa[4] = {a.x, a.y, a.z, a.w};
            float bb[4] = {b.x, b.y, b.z, b.w};
#pragma unroll
            for (int i = 0; i < 4; ++i)
#pragma unroll
                for (int j = 0; j < 4; ++j)
                    acc[i][j] = fmaf(aa[i], bb[j], acc[i][j]);
        }
    }

    if (MODE == 0) {
#pragma unroll
        for (int i = 0; i < 4; ++i) {
            int m = bm * 64 + ty * 4 + i;
            int n0 = bn * 64 + tx * 4;
            float4 o = {acc[i][0], acc[i][1], acc[i][2], acc[i][3]};
            *(float4*)(C + (size_t)m * N + n0) = o;
        }
    } else {
        const int n0 = bn * 64 + tx * 4;
        const int which = n0 >> 10;          // block-uniform (64 | 1024)
        const int h = (n0 >> 6) & 15;
        const int d = n0 & 63;
#pragma unroll
        for (int i = 0; i < 4; ++i) {
            int m = bm * 64 + ty * 4 + i;
            int b = m >> 12, l = m & 4095;   // b is pass-local
            size_t dst = ((size_t)(b * 16 + h) * 4096 + l) * 64 + d;
            if (which == 0) {
                float4 o = {phi_f(acc[i][0]), phi_f(acc[i][1]), phi_f(acc[i][2]), phi_f(acc[i][3])};
                *(float4*)(qb + dst) = o;
            } else if (which == 1) {
                float4 o = {phi_f(acc[i][0]), phi_f(acc[i][1]), phi_f(acc[i][2]), phi_f(acc[i][3])};
                *(float4*)(kb + dst) = o;
            } else {
                float4 o = {acc[i][0], acc[i][1], acc[i][2], acc[i][3]};
                *(float4*)(vb + dst) = o;
            }
        }
    }
}

// ---------------------------------------------------------------------------
// Phase A: per (bh, chunk): S_part[d][e] = sum_t k[t][d] v[t][e], z_part[d]
// ---------------------------------------------------------------------------
__global__ __launch_bounds__(256)
void chunk_kv(const float* __restrict__ kb, const float* __restrict__ vb,
              float* __restrict__ S, float* __restrict__ z)
{
    const int c = blockIdx.x, bh = blockIdx.y;
    const float* kc = kb + ((size_t)bh * L_SEQc + c * CHUNKc) * D_HEADc;
    const float* vc = vb + ((size_t)bh * L_SEQc + c * CHUNKc) * D_HEADc;
    __shared__ float ks[32][64];
    __shared__ float vs[32][64];
    const int tid = threadIdx.x;
    const int eg = (tid & 15) * 4;
    const int dg = (tid >> 4) * 4;
    float acc[4][4] = {};
    float zacc = 0.0f;
    const int base = tid * 8;

    for (int t0 = 0; t0 < CHUNKc; t0 += 32) {
        __syncthreads();
        *(float4*)(&ks[0][0] + base)     = *(const float4*)(kc + t0 * 64 + base);
        *(float4*)(&ks[0][0] + base + 4) = *(const float4*)(kc + t0 * 64 + base + 4);
        *(float4*)(&vs[0][0] + base)     = *(const float4*)(vc + t0 * 64 + base);
        *(float4*)(&vs[0][0] + base + 4) = *(const float4*)(vc + t0 * 64 + base + 4);
        __syncthreads();
#pragma unroll
        for (int t = 0; t < 32; ++t) {
            float4 kf = *(const float4*)&ks[t][dg];
            float4 vf = *(const float4*)&vs[t][eg];
            float ka[4] = {kf.x, kf.y, kf.z, kf.w};
            float va[4] = {vf.x, vf.y, vf.z, vf.w};
#pragma unroll
            for (int i = 0; i < 4; ++i)
#pragma unroll
                for (int j = 0; j < 4; ++j)
                    acc[i][j] = fmaf(ka[i], va[j], acc[i][j]);
        }
        if (tid < 64) {
#pragma unroll
            for (int t = 0; t < 32; ++t) zacc += ks[t][tid];
        }
    }
    float* Sp = S + (size_t)(bh * NCHUNKc + c) * 4096;
#pragma unroll
    for (int i = 0; i < 4; ++i) {
        float4 o = {acc[i][0], acc[i][1], acc[i][2], acc[i][3]};
        *(float4*)(Sp + (dg + i) * 64 + eg) = o;
    }
    if (tid < 64) z[(bh * NCHUNKc + c) * 64 + tid] = zacc;
}

// ---------------------------------------------------------------------------
// Phase B: exclusive prefix over chunks, parallel over entries.
// grid (17, BH): sections 0-15 cover the 4096 S entries (256 each);
// section 16 covers the 64 z entries.
// ---------------------------------------------------------------------------
__global__ __launch_bounds__(256)
void prefix_chunks(float* __restrict__ S, float* __restrict__ z)
{
    const int sec = blockIdx.x, bh = blockIdx.y;
    const int tid = threadIdx.x;
    if (sec < 16) {
        float* base = S + (size_t)bh * NCHUNKc * 4096 + sec * 256 + tid;
        float acc = 0.0f;
#pragma unroll
        for (int c = 0; c < NCHUNKc; ++c) {
            float t = base[(size_t)c * 4096];
            base[(size_t)c * 4096] = acc;
            acc += t;
        }
    } else if (tid < 64) {
        float* base = z + (size_t)bh * NCHUNKc * 64 + tid;
        float acc = 0.0f;
#pragma unroll
        for (int c = 0; c < NCHUNKc; ++c) {
            float t = base[c * 64];
            base[c * 64] = acc;
            acc += t;
        }
    }
}

// ---------------------------------------------------------------------------
// Phase C: per (bh, chunk):
//   out[t] = ( q_t @ S_pre + sum_{t'<=t} (q_t.k_t') v_t' ) / max(q_t.z_cum, EPS)
// 6 tiles of 32: tiles 0-1 = prefix-state ("P" = q slice), tiles 2-5 = causal
// intra-chunk. den folded in via zden (z_pre slice or 1.0).
// ---------------------------------------------------------------------------
__global__ __launch_bounds__(256)
void chunk_out(const float* __restrict__ qb, const float* __restrict__ kb,
               const float* __restrict__ vb, const float* __restrict__ S,
               const float* __restrict__ z, float* __restrict__ att)
{
    const int c = blockIdx.x, bh = blockIdx.y;
    const int b = bh >> 4, h = bh & 15;      // b is pass-local
    const float* qc = qb + ((size_t)bh * L_SEQc + c * CHUNKc) * D_HEADc;
    const float* kc = kb + ((size_t)bh * L_SEQc + c * CHUNKc) * D_HEADc;
    const float* vc = vb + ((size_t)bh * L_SEQc + c * CHUNKc) * D_HEADc;
    const float* Sp = S + (size_t)(bh * NCHUNKc + c) * 4096;
    const float* zp = z + (size_t)(bh * NCHUNKc + c) * 64;

    __shared__ float q_s[128][65];
    __shared__ float kt_s[32][65];
    __shared__ float pv_s[32][68];
    __shared__ float P_s[128][34];
    __shared__ float zden_s[32];

    const int tid = threadIdx.x;
    const int tx = tid & 15, ty = tid >> 4;

    // stage q chunk (128 x 64)
    {
        int t0 = tid >> 1;
        int d0 = (tid & 1) * 32;
        const float* qp = qc + t0 * 64 + d0;
#pragma unroll
        for (int w = 0; w < 32; ++w) q_s[t0][d0 + w] = qp[w];
    }

    float num[8][4];
    float dacc[8];
#pragma unroll
    for (int i = 0; i < 8; ++i) {
        dacc[i] = 0.0f;
#pragma unroll
        for (int j = 0; j < 4; ++j) num[i][j] = 0.0f;
    }

    const int st0 = tid >> 3;          // 0..31 (row for pv/kt staging)
    const int se0 = (tid & 7) * 8;     // 0..56

    for (int tile = 0; tile < 6; ++tile) {
        const bool pre = (tile < 2);
        __syncthreads();   // previous tile's reads complete (also covers q_s staging)
        if (pre) {
            const int dbase = tile * 32;
            *(float4*)&pv_s[st0][se0]     = *(const float4*)(Sp + (dbase + st0) * 64 + se0);
            *(float4*)&pv_s[st0][se0 + 4] = *(const float4*)(Sp + (dbase + st0) * 64 + se0 + 4);
            if (tid < 32) zden_s[tid] = zp[dbase + tid];
            __syncthreads();
#pragma unroll 4
            for (int t = 0; t < 32; ++t) {
                float4 vv = *(const float4*)&pv_s[t][tx * 4];
                float zw = zden_s[t];
#pragma unroll
                for (int i = 0; i < 8; ++i) {
                    float p = q_s[ty * 8 + i][dbase + t];
                    num[i][0] = fmaf(p, vv.x, num[i][0]);
                    num[i][1] = fmaf(p, vv.y, num[i][1]);
                    num[i][2] = fmaf(p, vv.z, num[i][2]);
                    num[i][3] = fmaf(p, vv.w, num[i][3]);
                    dacc[i] = fmaf(p, zw, dacc[i]);
                }
            }
        } else {
            const int tb = (tile - 2) * 32;
            *(float4*)&pv_s[st0][se0]     = *(const float4*)(vc + (tb + st0) * 64 + se0);
            *(float4*)&pv_s[st0][se0 + 4] = *(const float4*)(vc + (tb + st0) * 64 + se0 + 4);
            {
                const float* kp = kc + (tb + st0) * 64 + se0;
#pragma unroll
                for (int w = 0; w < 8; ++w) kt_s[st0][se0 + w] = kp[w];
            }
            __syncthreads();
            // scores: rows ty*8+i, cols tx*2+j
            float sc[8][2];
#pragma unroll
            for (int i = 0; i < 8; ++i) { sc[i][0] = 0.0f; sc[i][1] = 0.0f; }
#pragma unroll 8
            for (int d = 0; d < 64; ++d) {
                float kv0 = kt_s[tx * 2 + 0][d];
                float kv1 = kt_s[tx * 2 + 1][d];
#pragma unroll
                for (int i = 0; i < 8; ++i) {
                    float qv = q_s[ty * 8 + i][d];
                    sc[i][0] = fmaf(qv, kv0, sc[i][0]);
                    sc[i][1] = fmaf(qv, kv1, sc[i][1]);
                }
            }
#pragma unroll
            for (int i = 0; i < 8; ++i) {
                int r = ty * 8 + i;
#pragma unroll
                for (int j = 0; j < 2; ++j) {
                    int col = tx * 2 + j;
                    P_s[r][col] = (tb + col <= r) ? sc[i][j] : 0.0f;
                }
            }
            __syncthreads();
#pragma unroll 4
            for (int t = 0; t < 32; ++t) {
                float4 vv = *(const float4*)&pv_s[t][tx * 4];
#pragma unroll
                for (int i = 0; i < 8; ++i) {
                    float p = P_s[ty * 8 + i][t];
                    num[i][0] = fmaf(p, vv.x, num[i][0]);
                    num[i][1] = fmaf(p, vv.y, num[i][1]);
                    num[i][2] = fmaf(p, vv.z, num[i][2]);
                    num[i][3] = fmaf(p, vv.w, num[i][3]);
                    dacc[i] += p;   // zden == 1
                }
            }
        }
    }

    float* attp = att + ((size_t)b * L_SEQc + c * CHUNKc) * 1024 + h * 64;
#pragma unroll
    for (int i = 0; i < 8; ++i) {
        int r = ty * 8 + i;
        float inv = 1.0f / fmaxf(dacc[i], EPSc);
        float4 o = {num[i][0] * inv, num[i][1] * inv, num[i][2] * inv, num[i][3] * inv};
        *(float4*)(attp + (size_t)r * 1024 + tx * 4) = o;
    }
}

// ---------------------------------------------------------------------------
extern "C" void kernel_launch(void* const* d_in, const int* in_sizes, int n_in,
                              void* d_out, int out_size, void* d_ws, size_t ws_size,
                              hipStream_t stream) {
    const float* x     = (const float*)d_in[0];
    const float* w_qkv = (const float*)d_in[1];
    const float* w_out = (const float*)d_in[2];
    float* out = (float*)d_out;

    // dynamic batch-pass count to fit ws_size (deterministic per call)
    const size_t avail = ws_size / sizeof(float);
    int Bp = (avail >= 4 * WS_PER_B) ? 4 : (avail >= 2 * WS_PER_B) ? 2 : 1;

    float* ws  = (float*)d_ws;
    float* qb  = ws;
    float* kb  = qb + Bp * QKV_PER_B;
    float* vb  = kb + Bp * QKV_PER_B;
    float* att = vb + Bp * QKV_PER_B;
    float* S   = att + Bp * ATT_PER_B;
    float* z   = S + Bp * S_PER_B;

    const int Mp = Bp * 4096;
    const int BHp = Bp * 16;

    for (int b0 = 0; b0 < B_SZc; b0 += Bp) {
        const float* xp = x + (size_t)b0 * 4096 * 1024;

        // 1) QKV projection + phi + scatter to (b,h,l,d)
        dim3 g1(3072 / 64, Mp / 64);
        gemm_nt<1><<<g1, 256, 0, stream>>>(xp, w_qkv, nullptr, Mp, 3072, 1024, qb, kb, vb);

        // 2) per-chunk KV outer-product sums
        dim3 g2(NCHUNKc, BHp);
        chunk_kv<<<g2, 256, 0, stream>>>(kb, vb, S, z);

        // 3) exclusive prefix over chunks
        prefix_chunks<<<dim3(17, BHp), 256, 0, stream>>>(S, z);

        // 4) per-chunk attention output
        chunk_out<<<g2, 256, 0, stream>>>(qb, kb, vb, S, z, att);

        // 5) output projection
        dim3 g3(1024 / 64, Mp / 64);
        gemm_nt<0><<<g3, 256, 0, stream>>>(att, w_out, out + (size_t)b0 * 4096 * 1024, Mp, 1024, 1024,
                                           nullptr, nullptr, nullptr);
    }
}

// Round 6
// 610.108 us; speedup vs baseline: 3.4634x; 3.4634x over previous
//
#include <hip/hip_runtime.h>
#include <hip/hip_bf16.h>
#include <math.h>

#define D_MODELc 1024
#define N_HEADSc 16
#define D_HEADc  64
#define B_SZc    4
#define L_SEQc   4096
#define EPSc     1e-6f
#define CHUNKc   128
#define NCHUNKc  (L_SEQc / CHUNKc)   // 32

// per-batch element counts
#define QKV_PER_B  4194304ull        // 16*4096*64
#define ATT_PER_B  4194304ull        // 4096*1024
#define X_PER_B    4194304ull        // 4096*1024
#define S_PER_B    2097152ull        // 16*32*64*64
#define Z_PER_B    32768ull          // 16*32*64

typedef __attribute__((ext_vector_type(8))) short s16x8;   // 8 bf16 in 4 VGPRs
typedef __attribute__((ext_vector_type(4))) float f32x4;

__device__ __forceinline__ float phi_f(float x) {
    return x > 0.0f ? x + 1.0f : expf(x);   // elu(x)+1
}
__device__ __forceinline__ float bf2f(short h) {
    return __uint_as_float(((unsigned int)(unsigned short)h) << 16);
}
__device__ __forceinline__ short f2bf(float f) {
    unsigned int u = __float_as_uint(f);
    u = (u + 0x7FFFu + ((u >> 16) & 1u)) >> 16;   // RNE (finite inputs)
    return (short)u;
}

#define GLOAD16(ldsp, gp) \
    __builtin_amdgcn_global_load_lds((const __attribute__((address_space(1))) void*)(gp), \
                                     (__attribute__((address_space(3))) void*)(ldsp), 16, 0, 0)

// ---------------------------------------------------------------------------
// fp32 -> bf16 conversion (vectorized, grid-stride)
// ---------------------------------------------------------------------------
__global__ __launch_bounds__(256)
void cvt_f32_bf16(const float* __restrict__ in, short* __restrict__ out, int n)
{
    int i = (blockIdx.x * 256 + threadIdx.x) * 4;
    const int stride = gridDim.x * 256 * 4;
    for (; i < n; i += stride) {
        float4 v = *(const float4*)(in + i);
        short4 o = {f2bf(v.x), f2bf(v.y), f2bf(v.z), f2bf(v.w)};
        *(short4*)(out + i) = o;
    }
}

// ---------------------------------------------------------------------------
// bf16 MFMA GEMM, C[m][n] = sum_k A[m][k]*B[n][k]  (both row-major, NT)
// Tile 128x128, BK=32, 256 threads = 4 waves (2x2), each wave 64x64 (4x4 frags
// of 16x16x32). m97 structure: global_load_lds(16B) + 2 barriers per K-step.
// MODE 0: C fp32 row-major MxN.   MODE 1: qkv scatter, phi on q,k, bf16 out.
// ---------------------------------------------------------------------------
template<int MODE>
__global__ __launch_bounds__(256)
void gemm_bf16(const short* __restrict__ A, const short* __restrict__ Bm,
               int M, int N, int K, float* __restrict__ C,
               short* __restrict__ qb, short* __restrict__ kb, short* __restrict__ vb)
{
    __shared__ __align__(16) short lA[128 * 32];   // [row][k] linear, 8 KB
    __shared__ __align__(16) short lB[128 * 32];

    const int tid = threadIdx.x;
    const int lane = tid & 63;
    const int wave = tid >> 6;
    const int wr = wave >> 1, wc = wave & 1;       // 2x2 wave grid
    const int bm = blockIdx.y, bn = blockIdx.x;

    const short* Abase = A + (size_t)bm * 128 * K;
    const short* Bbase = Bm + (size_t)bn * 128 * K;

    f32x4 acc[4][4];
#pragma unroll
    for (int i = 0; i < 4; ++i)
#pragma unroll
        for (int j = 0; j < 4; ++j) acc[i][j] = (f32x4){0.f, 0.f, 0.f, 0.f};

    const int lr = lane & 15;            // frag row/col within 16
    const int lk = (lane >> 4) * 8;      // k sub-offset

    for (int k0 = 0; k0 < K; k0 += 32) {
        // stage A,B tiles (8 KB each) via async global->LDS, 16 B/lane
#pragma unroll
        for (int c2 = 0; c2 < 2; ++c2) {
            const int idx = c2 * 256 + tid;          // 0..511 -> 16B chunk
            const int row = idx >> 2;
            const int ks  = (idx & 3) * 8;
            GLOAD16(&lA[idx * 8], Abase + (size_t)row * K + k0 + ks);
            GLOAD16(&lB[idx * 8], Bbase + (size_t)row * K + k0 + ks);
        }
        __syncthreads();   // drains vmcnt -> tiles ready
        s16x8 af[4], bf[4];
#pragma unroll
        for (int m = 0; m < 4; ++m)
            af[m] = *(const s16x8*)&lA[(wr * 64 + m * 16 + lr) * 32 + lk];
#pragma unroll
        for (int n = 0; n < 4; ++n)
            bf[n] = *(const s16x8*)&lB[(wc * 64 + n * 16 + lr) * 32 + lk];
#pragma unroll
        for (int m = 0; m < 4; ++m)
#pragma unroll
            for (int n = 0; n < 4; ++n)
                acc[m][n] = __builtin_amdgcn_mfma_f32_16x16x32_bf16(af[m], bf[n], acc[m][n], 0, 0, 0);
        __syncthreads();   // protect LDS before next iteration's writes
    }

    // epilogue: C/D layout col = lane&15, row = (lane>>4)*4 + j
    const int cr0 = (lane >> 4) * 4;
    if (MODE == 0) {
#pragma unroll
        for (int m = 0; m < 4; ++m) {
#pragma unroll
            for (int n = 0; n < 4; ++n) {
                const int col = bn * 128 + wc * 64 + n * 16 + lr;
#pragma unroll
                for (int j = 0; j < 4; ++j) {
                    const int row = bm * 128 + wr * 64 + m * 16 + cr0 + j;
                    C[(size_t)row * N + col] = acc[m][n][j];
                }
            }
        }
    } else {
#pragma unroll
        for (int m = 0; m < 4; ++m) {
#pragma unroll
            for (int n = 0; n < 4; ++n) {
                const int col = bn * 128 + wc * 64 + n * 16 + lr;   // n in [0,3072)
                const int which = col >> 10;
                const int h = (col >> 6) & 15;
                const int d = col & 63;
#pragma unroll
                for (int j = 0; j < 4; ++j) {
                    const int row = bm * 128 + wr * 64 + m * 16 + cr0 + j;
                    const int b = row >> 12, l = row & 4095;        // pass-local b
                    const size_t dst = ((size_t)(b * 16 + h) * 4096 + l) * 64 + d;
                    const float v = acc[m][n][j];
                    if (which == 0)      qb[dst] = f2bf(phi_f(v));
                    else if (which == 1) kb[dst] = f2bf(phi_f(v));
                    else                 vb[dst] = f2bf(v);
                }
            }
        }
    }
}

// ---------------------------------------------------------------------------
// Phase A: per (bh, chunk): S_part[d][e] = sum_t k[t][d] v[t][e], z_part[d]
// (k, v stored bf16; math fp32)
// ---------------------------------------------------------------------------
__global__ __launch_bounds__(256)
void chunk_kv(const short* __restrict__ kbuf, const short* __restrict__ vbuf,
              float* __restrict__ S, float* __restrict__ z)
{
    const int c = blockIdx.x, bh = blockIdx.y;
    const short* kc = kbuf + ((size_t)bh * L_SEQc + c * CHUNKc) * D_HEADc;
    const short* vc = vbuf + ((size_t)bh * L_SEQc + c * CHUNKc) * D_HEADc;
    __shared__ float ks[32][64];
    __shared__ float vs[32][64];
    const int tid = threadIdx.x;
    const int eg = (tid & 15) * 4;
    const int dg = (tid >> 4) * 4;
    float acc[4][4] = {};
    float zacc = 0.0f;
    const int base = tid * 8;

    for (int t0 = 0; t0 < CHUNKc; t0 += 32) {
        __syncthreads();
        {
            s16x8 kv = *(const s16x8*)(kc + t0 * 64 + base);
            s16x8 vv = *(const s16x8*)(vc + t0 * 64 + base);
#pragma unroll
            for (int j = 0; j < 8; ++j) {
                (&ks[0][0])[base + j] = bf2f(kv[j]);
                (&vs[0][0])[base + j] = bf2f(vv[j]);
            }
        }
        __syncthreads();
#pragma unroll
        for (int t = 0; t < 32; ++t) {
            float4 kf = *(const float4*)&ks[t][dg];
            float4 vf = *(const float4*)&vs[t][eg];
            float ka[4] = {kf.x, kf.y, kf.z, kf.w};
            float va[4] = {vf.x, vf.y, vf.z, vf.w};
#pragma unroll
            for (int i = 0; i < 4; ++i)
#pragma unroll
                for (int j = 0; j < 4; ++j)
                    acc[i][j] = fmaf(ka[i], va[j], acc[i][j]);
        }
        if (tid < 64) {
#pragma unroll
            for (int t = 0; t < 32; ++t) zacc += ks[t][tid];
        }
    }
    float* Sp = S + (size_t)(bh * NCHUNKc + c) * 4096;
#pragma unroll
    for (int i = 0; i < 4; ++i) {
        float4 o = {acc[i][0], acc[i][1], acc[i][2], acc[i][3]};
        *(float4*)(Sp + (dg + i) * 64 + eg) = o;
    }
    if (tid < 64) z[(bh * NCHUNKc + c) * 64 + tid] = zacc;
}

// ---------------------------------------------------------------------------
// Phase B: exclusive prefix over chunks, parallel over entries.
// ---------------------------------------------------------------------------
__global__ __launch_bounds__(256)
void prefix_chunks(float* __restrict__ S, float* __restrict__ z)
{
    const int sec = blockIdx.x, bh = blockIdx.y;
    const int tid = threadIdx.x;
    if (sec < 16) {
        float* base = S + (size_t)bh * NCHUNKc * 4096 + sec * 256 + tid;
        float acc = 0.0f;
#pragma unroll
        for (int c = 0; c < NCHUNKc; ++c) {
            float t = base[(size_t)c * 4096];
            base[(size_t)c * 4096] = acc;
            acc += t;
        }
    } else if (tid < 64) {
        float* base = z + (size_t)bh * NCHUNKc * 64 + tid;
        float acc = 0.0f;
#pragma unroll
        for (int c = 0; c < NCHUNKc; ++c) {
            float t = base[c * 64];
            base[c * 64] = acc;
            acc += t;
        }
    }
}

// ---------------------------------------------------------------------------
// Phase C: per (bh, chunk):
//   out[t] = ( q_t @ S_pre + sum_{t'<=t} (q_t.k_t') v_t' ) / max(q_t.z_cum, EPS)
// q,k,v bf16 in; att bf16 out; S/z and all math fp32.
// ---------------------------------------------------------------------------
__global__ __launch_bounds__(256)
void chunk_out(const short* __restrict__ qbuf, const short* __restrict__ kbuf,
               const short* __restrict__ vbuf, const float* __restrict__ S,
               const float* __restrict__ z, short* __restrict__ att)
{
    const int c = blockIdx.x, bh = blockIdx.y;
    const int b = bh >> 4, h = bh & 15;      // b is pass-local
    const short* qc = qbuf + ((size_t)bh * L_SEQc + c * CHUNKc) * D_HEADc;
    const short* kc = kbuf + ((size_t)bh * L_SEQc + c * CHUNKc) * D_HEADc;
    const short* vc = vbuf + ((size_t)bh * L_SEQc + c * CHUNKc) * D_HEADc;
    const float* Sp = S + (size_t)(bh * NCHUNKc + c) * 4096;
    const float* zp = z + (size_t)(bh * NCHUNKc + c) * 64;

    __shared__ float q_s[128][65];
    __shared__ float kt_s[32][65];
    __shared__ float pv_s[32][68];
    __shared__ float P_s[128][34];
    __shared__ float zden_s[32];

    const int tid = threadIdx.x;
    const int tx = tid & 15, ty = tid >> 4;

    // stage q chunk (128 x 64), bf16 -> fp32
    {
        int t0 = tid >> 1;
        int d0 = (tid & 1) * 32;
        const short* qp = qc + t0 * 64 + d0;
#pragma unroll
        for (int w = 0; w < 32; w += 8) {
            s16x8 v = *(const s16x8*)(qp + w);
#pragma unroll
            for (int j = 0; j < 8; ++j) q_s[t0][d0 + w + j] = bf2f(v[j]);
        }
    }

    float num[8][4];
    float dacc[8];
#pragma unroll
    for (int i = 0; i < 8; ++i) {
        dacc[i] = 0.0f;
#pragma unroll
        for (int j = 0; j < 4; ++j) num[i][j] = 0.0f;
    }

    const int st0 = tid >> 3;          // 0..31
    const int se0 = (tid & 7) * 8;     // 0..56

    for (int tile = 0; tile < 6; ++tile) {
        const bool pre = (tile < 2);
        __syncthreads();
        if (pre) {
            const int dbase = tile * 32;
            *(float4*)&pv_s[st0][se0]     = *(const float4*)(Sp + (dbase + st0) * 64 + se0);
            *(float4*)&pv_s[st0][se0 + 4] = *(const float4*)(Sp + (dbase + st0) * 64 + se0 + 4);
            if (tid < 32) zden_s[tid] = zp[dbase + tid];
            __syncthreads();
#pragma unroll 4
            for (int t = 0; t < 32; ++t) {
                float4 vv = *(const float4*)&pv_s[t][tx * 4];
                float zw = zden_s[t];
#pragma unroll
                for (int i = 0; i < 8; ++i) {
                    float p = q_s[ty * 8 + i][dbase + t];
                    num[i][0] = fmaf(p, vv.x, num[i][0]);
                    num[i][1] = fmaf(p, vv.y, num[i][1]);
                    num[i][2] = fmaf(p, vv.z, num[i][2]);
                    num[i][3] = fmaf(p, vv.w, num[i][3]);
                    dacc[i] = fmaf(p, zw, dacc[i]);
                }
            }
        } else {
            const int tb = (tile - 2) * 32;
            {
                s16x8 vv8 = *(const s16x8*)(vc + (tb + st0) * 64 + se0);
                s16x8 kk8 = *(const s16x8*)(kc + (tb + st0) * 64 + se0);
#pragma unroll
                for (int j = 0; j < 8; ++j) {
                    pv_s[st0][se0 + j] = bf2f(vv8[j]);
                    kt_s[st0][se0 + j] = bf2f(kk8[j]);
                }
            }
            __syncthreads();
            float sc[8][2];
#pragma unroll
            for (int i = 0; i < 8; ++i) { sc[i][0] = 0.0f; sc[i][1] = 0.0f; }
#pragma unroll 8
            for (int d = 0; d < 64; ++d) {
                float kv0 = kt_s[tx * 2 + 0][d];
                float kv1 = kt_s[tx * 2 + 1][d];
#pragma unroll
                for (int i = 0; i < 8; ++i) {
                    float qv = q_s[ty * 8 + i][d];
                    sc[i][0] = fmaf(qv, kv0, sc[i][0]);
                    sc[i][1] = fmaf(qv, kv1, sc[i][1]);
                }
            }
#pragma unroll
            for (int i = 0; i < 8; ++i) {
                int r = ty * 8 + i;
#pragma unroll
                for (int j = 0; j < 2; ++j) {
                    int col = tx * 2 + j;
                    P_s[r][col] = (tb + col <= r) ? sc[i][j] : 0.0f;
                }
            }
            __syncthreads();
#pragma unroll 4
            for (int t = 0; t < 32; ++t) {
                float4 vv = *(const float4*)&pv_s[t][tx * 4];
#pragma unroll
                for (int i = 0; i < 8; ++i) {
                    float p = P_s[ty * 8 + i][t];
                    num[i][0] = fmaf(p, vv.x, num[i][0]);
                    num[i][1] = fmaf(p, vv.y, num[i][1]);
                    num[i][2] = fmaf(p, vv.z, num[i][2]);
                    num[i][3] = fmaf(p, vv.w, num[i][3]);
                    dacc[i] += p;
                }
            }
        }
    }

    short* attp = att + ((size_t)b * L_SEQc + c * CHUNKc) * 1024 + h * 64;
#pragma unroll
    for (int i = 0; i < 8; ++i) {
        int r = ty * 8 + i;
        float inv = 1.0f / fmaxf(dacc[i], EPSc);
        short4 o = {f2bf(num[i][0] * inv), f2bf(num[i][1] * inv),
                    f2bf(num[i][2] * inv), f2bf(num[i][3] * inv)};
        *(short4*)(attp + (size_t)r * 1024 + tx * 4) = o;
    }
}

// ---------------------------------------------------------------------------
extern "C" void kernel_launch(void* const* d_in, const int* in_sizes, int n_in,
                              void* d_out, int out_size, void* d_ws, size_t ws_size,
                              hipStream_t stream) {
    const float* x     = (const float*)d_in[0];
    const float* w_qkv = (const float*)d_in[1];
    const float* w_out = (const float*)d_in[2];
    float* out = (float*)d_out;

    // workspace budget (bytes): fixed weights + per-batch regions
    const size_t fixedB = 2ull * (3072 * 1024 + 1024 * 1024);
    const size_t perB   = 2ull * X_PER_B + 2ull * 3 * QKV_PER_B + 2ull * ATT_PER_B
                        + 4ull * S_PER_B + 4ull * Z_PER_B;
    int Bp = 1;
    if (ws_size >= fixedB + 4 * perB + 65536) Bp = 4;
    else if (ws_size >= fixedB + 2 * perB + 65536) Bp = 2;

    char* p = (char*)d_ws;
    short* wqkvb = (short*)p; p += 2ull * 3072 * 1024;
    short* woutb = (short*)p; p += 2ull * 1024 * 1024;
    short* xb    = (short*)p; p += 2ull * X_PER_B * Bp;
    short* qb    = (short*)p; p += 2ull * QKV_PER_B * Bp;
    short* kb    = (short*)p; p += 2ull * QKV_PER_B * Bp;
    short* vb    = (short*)p; p += 2ull * QKV_PER_B * Bp;
    short* attb  = (short*)p; p += 2ull * ATT_PER_B * Bp;
    float* S     = (float*)p; p += 4ull * S_PER_B * Bp;
    float* z     = (float*)p;

    const int Mp = Bp * 4096;
    const int BHp = Bp * 16;

    // weights -> bf16 (once per call)
    cvt_f32_bf16<<<dim3(1024), 256, 0, stream>>>(w_qkv, wqkvb, 3072 * 1024);
    cvt_f32_bf16<<<dim3(512), 256, 0, stream>>>(w_out, woutb, 1024 * 1024);

    for (int b0 = 0; b0 < B_SZc; b0 += Bp) {
        const float* xp = x + (size_t)b0 * 4096 * 1024;

        // x -> bf16
        cvt_f32_bf16<<<dim3(2048), 256, 0, stream>>>(xp, xb, Mp * 1024);

        // 1) QKV projection (bf16 MFMA) + phi + scatter
        dim3 g1(3072 / 128, Mp / 128);
        gemm_bf16<1><<<g1, 256, 0, stream>>>(xb, wqkvb, Mp, 3072, 1024, nullptr, qb, kb, vb);

        // 2) per-chunk KV outer-product sums
        dim3 g2(NCHUNKc, BHp);
        chunk_kv<<<g2, 256, 0, stream>>>(kb, vb, S, z);

        // 3) exclusive prefix over chunks
        prefix_chunks<<<dim3(17, BHp), 256, 0, stream>>>(S, z);

        // 4) per-chunk attention output (att in bf16)
        chunk_out<<<g2, 256, 0, stream>>>(qb, kb, vb, S, z, attb);

        // 5) output projection (bf16 MFMA), fp32 out
        dim3 g3(1024 / 128, Mp / 128);
        gemm_bf16<0><<<g3, 256, 0, stream>>>(attb, woutb, Mp, 1024, 1024,
                                             out + (size_t)b0 * 4096 * 1024,
                                             nullptr, nullptr, nullptr);
    }
}

// Round 7
// 440.667 us; speedup vs baseline: 4.7951x; 1.3845x over previous
//
#include <hip/hip_runtime.h>
#include <hip/hip_bf16.h>
#include <math.h>

#define B_SZc    4
#define L_SEQc   4096
#define EPSc     1e-6f
#define CHUNKc   128
#define NCHUNKc  32

// per-batch element counts
#define QKV_PER_B  4194304ull        // 16*4096*64
#define ATT_PER_B  4194304ull
#define X_PER_B    4194304ull
#define S_PER_B    2097152ull        // 16*32*64*64
#define Z_PER_B    32768ull

typedef __attribute__((ext_vector_type(8))) short s16x8;
typedef __attribute__((ext_vector_type(4))) short s16x4;
typedef __attribute__((ext_vector_type(4))) float f32x4;

__device__ __forceinline__ float phi_f(float x) {
    return x > 0.0f ? x + 1.0f : expf(x);   // elu(x)+1
}
__device__ __forceinline__ float bf2f(short h) {
    return __uint_as_float(((unsigned int)(unsigned short)h) << 16);
}
__device__ __forceinline__ short f2bf(float f) {
    unsigned int u = __float_as_uint(f);
    u = (u + 0x7FFFu + ((u >> 16) & 1u)) >> 16;   // RNE
    return (short)u;
}

#define GLOAD16(ldsp, gp) \
    __builtin_amdgcn_global_load_lds((const __attribute__((address_space(1))) void*)(gp), \
                                     (__attribute__((address_space(3))) void*)(ldsp), 16, 0, 0)

// ---------------------------------------------------------------------------
__global__ __launch_bounds__(256)
void cvt_f32_bf16(const float* __restrict__ in, short* __restrict__ out, int n)
{
    int i = (blockIdx.x * 256 + threadIdx.x) * 4;
    const int stride = gridDim.x * 256 * 4;
    for (; i < n; i += stride) {
        float4 v = *(const float4*)(in + i);
        short4 o = {f2bf(v.x), f2bf(v.y), f2bf(v.z), f2bf(v.w)};
        *(short4*)(out + i) = o;
    }
}

// ---------------------------------------------------------------------------
// bf16 MFMA GEMM NT (m97 structure). MODE 0: C fp32. MODE 1: qkv scatter:
// q normal (phi), k normal + transposed (phi), v transposed only.
// ---------------------------------------------------------------------------
template<int MODE>
__global__ __launch_bounds__(256)
void gemm_bf16(const short* __restrict__ A, const short* __restrict__ Bm,
               int M, int N, int K, float* __restrict__ C,
               short* __restrict__ qb, short* __restrict__ kb,
               short* __restrict__ kTb, short* __restrict__ vTb)
{
    __shared__ __align__(16) short lA[128 * 32];
    __shared__ __align__(16) short lB[128 * 32];

    const int tid = threadIdx.x;
    const int lane = tid & 63;
    const int wave = tid >> 6;
    const int wr = wave >> 1, wc = wave & 1;
    const int bm = blockIdx.y, bn = blockIdx.x;

    const short* Abase = A + (size_t)bm * 128 * K;
    const short* Bbase = Bm + (size_t)bn * 128 * K;

    f32x4 acc[4][4];
#pragma unroll
    for (int i = 0; i < 4; ++i)
#pragma unroll
        for (int j = 0; j < 4; ++j) acc[i][j] = (f32x4){0.f, 0.f, 0.f, 0.f};

    const int lr = lane & 15;
    const int lk = (lane >> 4) * 8;

    for (int k0 = 0; k0 < K; k0 += 32) {
#pragma unroll
        for (int c2 = 0; c2 < 2; ++c2) {
            const int idx = c2 * 256 + tid;
            const int row = idx >> 2;
            const int ks  = (idx & 3) * 8;
            GLOAD16(&lA[idx * 8], Abase + (size_t)row * K + k0 + ks);
            GLOAD16(&lB[idx * 8], Bbase + (size_t)row * K + k0 + ks);
        }
        __syncthreads();
        s16x8 af[4], bf[4];
#pragma unroll
        for (int m = 0; m < 4; ++m)
            af[m] = *(const s16x8*)&lA[(wr * 64 + m * 16 + lr) * 32 + lk];
#pragma unroll
        for (int n = 0; n < 4; ++n)
            bf[n] = *(const s16x8*)&lB[(wc * 64 + n * 16 + lr) * 32 + lk];
#pragma unroll
        for (int m = 0; m < 4; ++m)
#pragma unroll
            for (int n = 0; n < 4; ++n)
                acc[m][n] = __builtin_amdgcn_mfma_f32_16x16x32_bf16(af[m], bf[n], acc[m][n], 0, 0, 0);
        __syncthreads();
    }

    const int cr0 = (lane >> 4) * 4;
    if (MODE == 0) {
#pragma unroll
        for (int m = 0; m < 4; ++m)
#pragma unroll
            for (int n = 0; n < 4; ++n) {
                const int col = bn * 128 + wc * 64 + n * 16 + lr;
#pragma unroll
                for (int j = 0; j < 4; ++j) {
                    const int row = bm * 128 + wr * 64 + m * 16 + cr0 + j;
                    C[(size_t)row * N + col] = acc[m][n][j];
                }
            }
    } else {
#pragma unroll
        for (int m = 0; m < 4; ++m)
#pragma unroll
            for (int n = 0; n < 4; ++n) {
                const int col = bn * 128 + wc * 64 + n * 16 + lr;
                const int which = col >> 10;
                const int h = (col >> 6) & 15;
                const int d = col & 63;
                const int row0 = bm * 128 + wr * 64 + m * 16 + cr0;
                const int b = row0 >> 12;
                const int l0 = row0 & 4095;
                const size_t bh64 = (size_t)(b * 16 + h);
                if (which == 0) {
#pragma unroll
                    for (int j = 0; j < 4; ++j)
                        qb[(bh64 * 4096 + l0 + j) * 64 + d] = f2bf(phi_f(acc[m][n][j]));
                } else if (which == 1) {
                    s16x4 pk;
#pragma unroll
                    for (int j = 0; j < 4; ++j) {
                        short v = f2bf(phi_f(acc[m][n][j]));
                        kb[(bh64 * 4096 + l0 + j) * 64 + d] = v;
                        pk[j] = v;
                    }
                    *(s16x4*)(kTb + (bh64 * 64 + d) * 4096 + l0) = pk;
                } else {
                    s16x4 pv;
#pragma unroll
                    for (int j = 0; j < 4; ++j) pv[j] = f2bf(acc[m][n][j]);
                    *(s16x4*)(vTb + (bh64 * 64 + d) * 4096 + l0) = pv;
                }
            }
    }
}

// ---------------------------------------------------------------------------
// Phase A (MFMA): per (bh, chunk): ST[e][d] = sum_t v[t][e]*k[t][d]; z[d].
// 4 waves per block, one chunk per wave, operands direct from global.
// A = V^T rows (e), B = K^T rows (d). z via ones-A MFMA trick.
// ---------------------------------------------------------------------------
__global__ __launch_bounds__(256)
void chunk_kv(const short* __restrict__ kTb, const short* __restrict__ vTb,
              float* __restrict__ ST, float* __restrict__ z)
{
    const int wave = threadIdx.x >> 6;
    const int lane = threadIdx.x & 63;
    const int c = blockIdx.x * 4 + wave;
    const int bh = blockIdx.y;
    const short* kT = kTb + (size_t)bh * 64 * 4096 + c * CHUNKc;
    const short* vT = vTb + (size_t)bh * 64 * 4096 + c * CHUNKc;
    const int lr = lane & 15;
    const int lk = (lane >> 4) * 8;

    f32x4 acc[4][4];
    f32x4 accz[4];
#pragma unroll
    for (int m = 0; m < 4; ++m) {
        accz[m] = (f32x4){0.f, 0.f, 0.f, 0.f};
#pragma unroll
        for (int n = 0; n < 4; ++n) acc[m][n] = (f32x4){0.f, 0.f, 0.f, 0.f};
    }
    s16x8 ones;
#pragma unroll
    for (int j = 0; j < 8; ++j) ones[j] = (short)0x3F80;   // bf16 1.0

#pragma unroll
    for (int ks = 0; ks < 4; ++ks) {
        const int t0 = ks * 32 + lk;
        s16x8 a[4], b[4];
#pragma unroll
        for (int m = 0; m < 4; ++m)
            a[m] = *(const s16x8*)(vT + (size_t)(m * 16 + lr) * 4096 + t0);
#pragma unroll
        for (int n = 0; n < 4; ++n)
            b[n] = *(const s16x8*)(kT + (size_t)(n * 16 + lr) * 4096 + t0);
#pragma unroll
        for (int m = 0; m < 4; ++m)
#pragma unroll
            for (int n = 0; n < 4; ++n)
                acc[m][n] = __builtin_amdgcn_mfma_f32_16x16x32_bf16(a[m], b[n], acc[m][n], 0, 0, 0);
#pragma unroll
        for (int n = 0; n < 4; ++n)
            accz[n] = __builtin_amdgcn_mfma_f32_16x16x32_bf16(ones, b[n], accz[n], 0, 0, 0);
    }

    float* STc = ST + ((size_t)bh * NCHUNKc + c) * 4096;
    const int er0 = (lane >> 4) * 4;
#pragma unroll
    for (int m = 0; m < 4; ++m)
#pragma unroll
        for (int n = 0; n < 4; ++n)
#pragma unroll
            for (int j = 0; j < 4; ++j)
                STc[(m * 16 + er0 + j) * 64 + n * 16 + lr] = acc[m][n][j];
    if (lane < 16) {
        float* zc = z + ((size_t)bh * NCHUNKc + c) * 64;
#pragma unroll
        for (int n = 0; n < 4; ++n) zc[n * 16 + lane] = accz[n][0];
    }
}

// ---------------------------------------------------------------------------
// Phase B: exclusive prefix over chunks (elementwise; ST transposed is fine).
// ---------------------------------------------------------------------------
__global__ __launch_bounds__(256)
void prefix_chunks(float* __restrict__ ST, float* __restrict__ z)
{
    const int sec = blockIdx.x, bh = blockIdx.y;
    const int tid = threadIdx.x;
    if (sec < 16) {
        float* base = ST + (size_t)bh * NCHUNKc * 4096 + sec * 256 + tid;
        float acc = 0.0f;
#pragma unroll
        for (int c = 0; c < NCHUNKc; ++c) {
            float t = base[(size_t)c * 4096];
            base[(size_t)c * 4096] = acc;
            acc += t;
        }
    } else if (tid < 64) {
        float* base = z + (size_t)bh * NCHUNKc * 64 + tid;
        float acc = 0.0f;
#pragma unroll
        for (int c = 0; c < NCHUNKc; ++c) {
            float t = base[c * 64];
            base[c * 64] = acc;
            acc += t;
        }
    }
}

// ---------------------------------------------------------------------------
// Phase C (MFMA): P = causal(QK^T) -> LDS fp32; den = rowsum(P)+q.z_pre;
// num = P@V + Q@(S_hi+S_lo); att = num/den.
// 4 waves: QK^T wave-tile 64x64 (wr,wc); PV/QS wave-tile 64x32.
// ---------------------------------------------------------------------------
__global__ __launch_bounds__(256)
void chunk_out(const short* __restrict__ qb, const short* __restrict__ kb,
               const short* __restrict__ vTb, const float* __restrict__ ST,
               const float* __restrict__ z, short* __restrict__ attb)
{
    const int c = blockIdx.x, bh = blockIdx.y;
    const int b = bh >> 4, h = bh & 15;
    const short* qc = qb + ((size_t)bh * L_SEQc + c * CHUNKc) * 64;
    const short* kc = kb + ((size_t)bh * L_SEQc + c * CHUNKc) * 64;
    const short* vT = vTb + (size_t)bh * 64 * 4096 + c * CHUNKc;
    const float* STp = ST + ((size_t)bh * NCHUNKc + c) * 4096;
    const float* zp  = z + ((size_t)bh * NCHUNKc + c) * 64;

    __shared__ float P[128][130];    // stride 130: writes 2-way (free), b64 reads ~4-way
    __shared__ float den_s[128];

    const int tid = threadIdx.x;
    const int lane = tid & 63;
    const int wave = tid >> 6;
    const int wr = wave >> 1, wc = wave & 1;
    const int lr = lane & 15;
    const int lg = lane >> 4;
    const int lk = lg * 8;
    const int cr0 = lg * 4;

    // ---- Phase 1: P = QK^T (NT, K=64), causal mask, write fp32 to LDS ----
    {
        f32x4 p[4][4];
#pragma unroll
        for (int m = 0; m < 4; ++m)
#pragma unroll
            for (int n = 0; n < 4; ++n) p[m][n] = (f32x4){0.f, 0.f, 0.f, 0.f};
#pragma unroll
        for (int ks = 0; ks < 2; ++ks) {
            s16x8 a[4], bfr[4];
#pragma unroll
            for (int m = 0; m < 4; ++m)
                a[m] = *(const s16x8*)(qc + (size_t)(wr * 64 + m * 16 + lr) * 64 + ks * 32 + lk);
#pragma unroll
            for (int n = 0; n < 4; ++n)
                bfr[n] = *(const s16x8*)(kc + (size_t)(wc * 64 + n * 16 + lr) * 64 + ks * 32 + lk);
#pragma unroll
            for (int m = 0; m < 4; ++m)
#pragma unroll
                for (int n = 0; n < 4; ++n)
                    p[m][n] = __builtin_amdgcn_mfma_f32_16x16x32_bf16(a[m], bfr[n], p[m][n], 0, 0, 0);
        }
#pragma unroll
        for (int m = 0; m < 4; ++m)
#pragma unroll
            for (int n = 0; n < 4; ++n) {
                const int cc = wc * 64 + n * 16 + lr;
#pragma unroll
                for (int j = 0; j < 4; ++j) {
                    const int r = wr * 64 + m * 16 + cr0 + j;
                    P[r][cc] = (cc <= r) ? p[m][n][j] : 0.0f;
                }
            }
    }
    __syncthreads();

    // ---- Phase 2: den[r] = rowsum(P[r]) + q_r . z_pre ----
    {
        const int r = tid >> 1;
        const int half = tid & 1;
        float s = 0.0f;
        const float* Pr = &P[r][half * 64];
#pragma unroll
        for (int t = 0; t < 64; t += 2) {
            float2 v2 = *(const float2*)&Pr[t];
            s += v2.x + v2.y;
        }
        const short* qr = qc + r * 64 + half * 32;
        const float* zh = zp + half * 32;
#pragma unroll
        for (int d0 = 0; d0 < 32; d0 += 8) {
            s16x8 qv = *(const s16x8*)(qr + d0);
#pragma unroll
            for (int j = 0; j < 8; ++j) s += bf2f(qv[j]) * zh[d0 + j];
        }
        s += __shfl_xor(s, 1);
        if (half == 0) den_s[r] = fmaxf(s, EPSc);
    }
    __syncthreads();

    // ---- Phase 3: num = P @ V^T  +  Q @ (S_hi + S_lo) ----
    f32x4 num[4][2];
#pragma unroll
    for (int m = 0; m < 4; ++m)
#pragma unroll
        for (int n = 0; n < 2; ++n) num[m][n] = (f32x4){0.f, 0.f, 0.f, 0.f};

    // k = 0..127: P (LDS fp32 -> bf16) x V^T (global)
#pragma unroll
    for (int ks = 0; ks < 4; ++ks) {
        const int t0 = ks * 32 + lk;
        s16x8 a[4];
#pragma unroll
        for (int m = 0; m < 4; ++m) {
            const float* pr = &P[wr * 64 + m * 16 + lr][t0];
            float2 f0 = *(const float2*)&pr[0];
            float2 f1 = *(const float2*)&pr[2];
            float2 f2 = *(const float2*)&pr[4];
            float2 f3 = *(const float2*)&pr[6];
            s16x8 av;
            av[0] = f2bf(f0.x); av[1] = f2bf(f0.y);
            av[2] = f2bf(f1.x); av[3] = f2bf(f1.y);
            av[4] = f2bf(f2.x); av[5] = f2bf(f2.y);
            av[6] = f2bf(f3.x); av[7] = f2bf(f3.y);
            a[m] = av;
        }
#pragma unroll
        for (int n = 0; n < 2; ++n) {
            s16x8 bv = *(const s16x8*)(vT + (size_t)(wc * 32 + n * 16 + lr) * 4096 + t0);
#pragma unroll
            for (int m = 0; m < 4; ++m)
                num[m][n] = __builtin_amdgcn_mfma_f32_16x16x32_bf16(a[m], bv, num[m][n], 0, 0, 0);
        }
    }

    // k = 128..255: Q x S_hi, Q x S_lo  (S^T fp32 global, hi/lo split)
#pragma unroll
    for (int kk = 0; kk < 2; ++kk) {
        s16x8 qa[4];
#pragma unroll
        for (int m = 0; m < 4; ++m)
            qa[m] = *(const s16x8*)(qc + (size_t)(wr * 64 + m * 16 + lr) * 64 + kk * 32 + lk);
#pragma unroll
        for (int n = 0; n < 2; ++n) {
            const float* sp = STp + (size_t)(wc * 32 + n * 16 + lr) * 64 + kk * 32 + lk;
            float4 s0 = *(const float4*)sp;
            float4 s1 = *(const float4*)(sp + 4);
            float sv[8] = {s0.x, s0.y, s0.z, s0.w, s1.x, s1.y, s1.z, s1.w};
            s16x8 bhi, blo;
#pragma unroll
            for (int j = 0; j < 8; ++j) {
                short hi = f2bf(sv[j]);
                bhi[j] = hi;
                blo[j] = f2bf(sv[j] - bf2f(hi));
            }
#pragma unroll
            for (int m = 0; m < 4; ++m) {
                num[m][n] = __builtin_amdgcn_mfma_f32_16x16x32_bf16(qa[m], bhi, num[m][n], 0, 0, 0);
                num[m][n] = __builtin_amdgcn_mfma_f32_16x16x32_bf16(qa[m], blo, num[m][n], 0, 0, 0);
            }
        }
    }

    // ---- epilogue ----
#pragma unroll
    for (int m = 0; m < 4; ++m)
#pragma unroll
        for (int n = 0; n < 2; ++n) {
            const int e = wc * 32 + n * 16 + lr;
#pragma unroll
            for (int j = 0; j < 4; ++j) {
                const int r = wr * 64 + m * 16 + cr0 + j;
                const float inv = 1.0f / den_s[r];
                attb[((size_t)(b * 4096 + c * CHUNKc + r)) * 1024 + h * 64 + e] =
                    f2bf(num[m][n][j] * inv);
            }
        }
}

// ---------------------------------------------------------------------------
extern "C" void kernel_launch(void* const* d_in, const int* in_sizes, int n_in,
                              void* d_out, int out_size, void* d_ws, size_t ws_size,
                              hipStream_t stream) {
    const float* x     = (const float*)d_in[0];
    const float* w_qkv = (const float*)d_in[1];
    const float* w_out = (const float*)d_in[2];
    float* out = (float*)d_out;

    const size_t fixedB = 2ull * (3072 * 1024 + 1024 * 1024);
    const size_t perB   = 2ull * X_PER_B + 2ull * 5 * QKV_PER_B + 2ull * ATT_PER_B
                        + 4ull * S_PER_B + 4ull * Z_PER_B;     // q,k,kT,vT = 4 + att... (5*QKV covers q,k,kT,vT + spare? no: exactly 4) -- see below
    // q,k,kT,vT -> 4 QKV-sized bf16 buffers
    const size_t perB_real = 2ull * X_PER_B + 2ull * 4 * QKV_PER_B + 2ull * ATT_PER_B
                           + 4ull * S_PER_B + 4ull * Z_PER_B;
    (void)perB;
    int Bp = 1;
    if (ws_size >= fixedB + 4 * perB_real + 65536) Bp = 4;
    else if (ws_size >= fixedB + 2 * perB_real + 65536) Bp = 2;

    char* p = (char*)d_ws;
    short* wqkvb = (short*)p; p += 2ull * 3072 * 1024;
    short* woutb = (short*)p; p += 2ull * 1024 * 1024;
    short* xb    = (short*)p; p += 2ull * X_PER_B * Bp;
    short* qb    = (short*)p; p += 2ull * QKV_PER_B * Bp;
    short* kb    = (short*)p; p += 2ull * QKV_PER_B * Bp;
    short* kTb   = (short*)p; p += 2ull * QKV_PER_B * Bp;
    short* vTb   = (short*)p; p += 2ull * QKV_PER_B * Bp;
    short* attb  = (short*)p; p += 2ull * ATT_PER_B * Bp;
    float* S     = (float*)p; p += 4ull * S_PER_B * Bp;
    float* z     = (float*)p;

    const int Mp = Bp * 4096;
    const int BHp = Bp * 16;

    cvt_f32_bf16<<<dim3(1024), 256, 0, stream>>>(w_qkv, wqkvb, 3072 * 1024);
    cvt_f32_bf16<<<dim3(512), 256, 0, stream>>>(w_out, woutb, 1024 * 1024);

    for (int b0 = 0; b0 < B_SZc; b0 += Bp) {
        const float* xp = x + (size_t)b0 * 4096 * 1024;

        cvt_f32_bf16<<<dim3(2048), 256, 0, stream>>>(xp, xb, Mp * 1024);

        // 1) QKV projection + phi + scatter (q, k, kT, vT)
        dim3 g1(3072 / 128, Mp / 128);
        gemm_bf16<1><<<g1, 256, 0, stream>>>(xb, wqkvb, Mp, 3072, 1024, nullptr,
                                             qb, kb, kTb, vTb);

        // 2) per-chunk KV outer products (MFMA) -> ST[e][d], z[d]
        chunk_kv<<<dim3(NCHUNKc / 4, BHp), 256, 0, stream>>>(kTb, vTb, S, z);

        // 3) exclusive prefix over chunks
        prefix_chunks<<<dim3(17, BHp), 256, 0, stream>>>(S, z);

        // 4) per-chunk attention output (MFMA)
        chunk_out<<<dim3(NCHUNKc, BHp), 256, 0, stream>>>(qb, kb, vTb, S, z, attb);

        // 5) output projection
        dim3 g3(1024 / 128, Mp / 128);
        gemm_bf16<0><<<g3, 256, 0, stream>>>(attb, woutb, Mp, 1024, 1024,
                                             out + (size_t)b0 * 4096 * 1024,
                                             nullptr, nullptr, nullptr, nullptr);
    }
}